// Round 12
// baseline (178.602 us; speedup 1.0000x reference)
//
#include <hip/hip_runtime.h>
#include <hip/hip_bf16.h>

#define NFEAT 1024
#define CELL_EMB 1024
#define DRUG_EMB 128
#define HID 200
#define NDOSES 9
#define N_MISSING 100
#define N_DRUGS 256
#define S 16
#define MUSTRIDE 12

typedef __hip_bfloat16 bf16;
typedef __attribute__((ext_vector_type(8))) short short8;
typedef __attribute__((ext_vector_type(4))) short short4v;
typedef __attribute__((ext_vector_type(4))) float float4v;
typedef __attribute__((ext_vector_type(2))) float float2v;

__device__ __forceinline__ float bf2f(short s) {
    unsigned u = ((unsigned)(unsigned short)s) << 16;
    return __builtin_bit_cast(float, u);
}
__device__ __forceinline__ short f2bf(float f) {
    unsigned u = __builtin_bit_cast(unsigned, f);
    unsigned r = (u + 0x7FFFu + ((u >> 16) & 1u)) >> 16;
    return (short)r;
}
template <bool F32>
__device__ __forceinline__ float ld(const void* p, int i) {
    if (F32) return ((const float*)p)[i];
    return bf2f(((const short*)p)[i]);
}
__device__ __forceinline__ float ldr(const void* p, int i, bool f32) {
    return f32 ? ((const float*)p)[i] : bf2f(((const short*)p)[i]);
}
__device__ __forceinline__ float softplusf(float x) {
    return (x > 20.f) ? x : log1pf(expf(x));
}

// Inline per-wave dtype sniff: W1[0:64] as ushorts, one L2 line.
__device__ __forceinline__ bool sniff_f32(const unsigned short* __restrict__ w1) {
    int lane = threadIdx.x & 63;
    unsigned short h = w1[lane];
    bool hit = ((lane & 1) == 0) && (((h >> 7) & 0xFFu) >= 130u);
    return __ballot(hit) != 0ull;
}

// ============================ FAST PATH ============================

#define GP_PRESENT 800                 // [0,800): c=b>>3, kc=b&7
#define GP_DC_END (GP_PRESENT + 256)   // [800,1056)
#define GP_PB_END (GP_DC_END + 25)     // [1056,1081): prepb, 6272 entries
#define GP_CZ_END (GP_PB_END + 40)     // [1081,1121): Cc zero
#define GP_TB_END (GP_CZ_END + 1)      // [1121,1122): epilogue tables

// one launch: present-partials + dc + prepb + Cc-zero + tables (all independent)
__global__ __launch_bounds__(256) void mega_prep_k(const void* __restrict__ CF,
                                                   const unsigned short* __restrict__ W1u,
                                                   const void* __restrict__ b1,
                                                   const void* __restrict__ drug_emb,
                                                   const void* __restrict__ Wf1,
                                                   const void* __restrict__ Wf2,
                                                   const void* __restrict__ bf1,
                                                   const void* __restrict__ bf2,
                                                   const void* __restrict__ Wf3,
                                                   float* __restrict__ P8,
                                                   float* __restrict__ Dc,
                                                   short8* __restrict__ Bf,
                                                   float* __restrict__ Cc,
                                                   float* __restrict__ bf1p,
                                                   float* __restrict__ bf2p,
                                                   float* __restrict__ wf3f) {
    bool f32 = sniff_f32(W1u);
    const void* W1 = (const void*)W1u;
    int blk = blockIdx.x, tid = threadIdx.x;

    if (blk < GP_PRESENT) {
        __shared__ float feat[128];
        int c = blk >> 3, kc = blk & 7;
        if (tid < 128) feat[tid] = ldr(CF, c * NFEAT + kc * 128 + tid, f32);
        __syncthreads();
        int j0 = tid * 4;
        float a0 = 0.f, a1 = 0.f, a2 = 0.f, a3 = 0.f;
        if (f32) {
            const float* w = (const float*)W1 + (size_t)(kc * 128) * CELL_EMB + j0;
#pragma unroll 8
            for (int k = 0; k < 128; ++k) {
                float4v wv = *(const float4v*)(w + (size_t)k * CELL_EMB);
                float fk = feat[k];
                a0 = fmaf(fk, wv[0], a0); a1 = fmaf(fk, wv[1], a1);
                a2 = fmaf(fk, wv[2], a2); a3 = fmaf(fk, wv[3], a3);
            }
        } else {
            const short* w = (const short*)W1 + (size_t)(kc * 128) * CELL_EMB + j0;
#pragma unroll 8
            for (int k = 0; k < 128; ++k) {
                short4v wv = *(const short4v*)(w + (size_t)k * CELL_EMB);
                float fk = feat[k];
                a0 = fmaf(fk, bf2f(wv[0]), a0); a1 = fmaf(fk, bf2f(wv[1]), a1);
                a2 = fmaf(fk, bf2f(wv[2]), a2); a3 = fmaf(fk, bf2f(wv[3]), a3);
            }
        }
        if (kc == 0) {
            a0 += ldr(b1, j0 + 0, f32); a1 += ldr(b1, j0 + 1, f32);
            a2 += ldr(b1, j0 + 2, f32); a3 += ldr(b1, j0 + 3, f32);
        }
        float4v o; o[0] = a0; o[1] = a1; o[2] = a2; o[3] = a3;
        *(float4v*)(P8 + ((size_t)(kc * N_MISSING + c)) * CELL_EMB + j0) = o;
    } else if (blk < GP_DC_END) {
        __shared__ float x[DRUG_EMB];
        __shared__ float red[4];
        int d = blk - GP_PRESENT;
        if (tid < DRUG_EMB) x[tid] = ldr(drug_emb, d * DRUG_EMB + tid, f32);
        __syncthreads();
        float ss = 0.f;
        if (tid < DRUG_EMB) ss = x[tid] * x[tid];
        for (int o = 32; o > 0; o >>= 1) ss += __shfl_down(ss, o, 64);
        if ((tid & 63) == 0) red[tid >> 6] = ss;
        __syncthreads();
        float inv = 1.f / fmaxf(sqrtf(red[0] + red[1] + red[2] + red[3]), 1e-12f);
        if (tid < HID) {
            float acc = 0.f;
#pragma unroll 8
            for (int k = 0; k < DRUG_EMB; ++k)
                acc = fmaf(x[k], ldr(Wf1, (CELL_EMB + k) * HID + tid, f32), acc);
            Dc[d * HID + tid] = acc * inv;
        }
    } else if (blk < GP_PB_END) {
        int t = (blk - GP_DC_END) * 256 + tid;
        if (t < 6272) {
            int l = t & 63, chunk = t >> 6;
            int p = chunk / 49, rem = chunk - p * 49;
            int nt = rem / 7, s = rem - nt * 7;
            int n = p * 112 + nt * 16 + (l & 15);
            int k0 = s * 32 + (l >> 4) * 8;
            short8 v;
#pragma unroll
            for (int j = 0; j < 8; ++j) {
                int k = k0 + j;
                v[j] = (k < HID && n < HID) ? f2bf(ldr(Wf2, k * HID + n, f32)) : (short)0;
            }
            Bf[t] = v;
        }
    } else if (blk < GP_CZ_END) {
        int i = (blk - GP_PB_END) * 1024 + tid * 4;
        if (i < 200 * HID) {
            float4v z; z[0] = 0.f; z[1] = 0.f; z[2] = 0.f; z[3] = 0.f;
            *(float4v*)(Cc + i) = z;
        }
    } else {
        // ---- epilogue tables: bf1p/bf2p (float[224], zero-padded),
        //      wf3f (float[224*10], dose-padded stride 10 for packed fp32 math)
        if (tid < 224) {
            bf1p[tid] = (tid < HID) ? ldr(bf1, tid, f32) : 0.f;
            bf2p[tid] = (tid < HID) ? ldr(bf2, tid, f32) : 0.f;
        }
        for (int t = tid; t < 2240; t += 256) {
            int n = t / 10, dd = t - n * 10;
            wf3f[t] = (n < HID && dd < NDOSES) ? ldr(Wf3, n * NDOSES + dd, f32) : 0.f;
        }
    }
}

// cc_k (norm fused): block (r, kc) sums the 8 P8 partials, computes the row
// inv-norm, then Cc[r][:] += (x_chunk @ Wf1_chunk) * inv.
__global__ __launch_bounds__(256) void cc_k(const unsigned short* __restrict__ W1u,
                                            const float* __restrict__ P8,
                                            const void* __restrict__ missing_emb,
                                            const void* __restrict__ Wf1,
                                            float* __restrict__ Cc) {
    __shared__ __align__(16) float x[128];
    __shared__ float red[4];
    bool f32 = sniff_f32(W1u);
    int r = blockIdx.x, kc = blockIdx.y, tid = threadIdx.x;
    int e0 = tid * 4;
    float4v v;
    if (r < N_MISSING) {
        v[0] = 0.f; v[1] = 0.f; v[2] = 0.f; v[3] = 0.f;
#pragma unroll
        for (int p = 0; p < 8; ++p) {
            float4v t = *(const float4v*)(P8 + ((size_t)(p * N_MISSING + r)) * CELL_EMB + e0);
            v[0] += t[0]; v[1] += t[1]; v[2] += t[2]; v[3] += t[3];
        }
        v[0] = fmaxf(v[0], 0.f); v[1] = fmaxf(v[1], 0.f);
        v[2] = fmaxf(v[2], 0.f); v[3] = fmaxf(v[3], 0.f);
    } else if (f32) {
        v = *(const float4v*)((const float*)missing_emb + (size_t)(r - N_MISSING) * CELL_EMB + e0);
    } else {
        short4v s = *(const short4v*)((const short*)missing_emb + (size_t)(r - N_MISSING) * CELL_EMB + e0);
        v[0] = bf2f(s[0]); v[1] = bf2f(s[1]); v[2] = bf2f(s[2]); v[3] = bf2f(s[3]);
    }
    if ((tid >> 5) == kc) *(float4v*)(x + (e0 - kc * 128)) = v;
    float ss = v[0] * v[0] + v[1] * v[1] + v[2] * v[2] + v[3] * v[3];
    for (int o = 32; o > 0; o >>= 1) ss += __shfl_down(ss, o, 64);
    if ((tid & 63) == 0) red[tid >> 6] = ss;
    __syncthreads();
    float inv = 1.f / fmaxf(sqrtf(red[0] + red[1] + red[2] + red[3]), 1e-12f);
    if (tid < HID) {
        float acc = 0.f;
        if (f32) {
            const float* w = (const float*)Wf1 + (size_t)(kc * 128) * HID + tid;
#pragma unroll 8
            for (int k = 0; k < 128; ++k)
                acc = fmaf(x[k], w[(size_t)k * HID], acc);
        } else {
            const short* w = (const short*)Wf1 + (size_t)(kc * 128) * HID + tid;
#pragma unroll 8
            for (int k = 0; k < 128; ++k)
                acc = fmaf(x[k], bf2f(w[(size_t)k * HID]), acc);
        }
        atomicAdd(&Cc[r * HID + tid], acc * inv);
    }
}

// ---- pair MFMA kernel (R11-proven structure; epilogue now packed fp32):
// MB=64, A-frags in registers reused across both passes; global Bf reads.
#define KSTEPS 7
#define NTP 7
#define KP 224
#define MB 64

__global__ __launch_bounds__(256) void pair_k(const float* __restrict__ Cc,
                                              const float* __restrict__ Dc,
                                              const float* __restrict__ bf1p,
                                              const float* __restrict__ bf2p,
                                              const float* __restrict__ wf3f,
                                              const short8* __restrict__ Bf,
                                              float* __restrict__ mu) {
    __shared__ float Crow[KP];
    __shared__ float bf2s[KP];
    __shared__ __align__(16) float wf3s[2240];   // [n][10], dose-padded
    int tid = threadIdx.x;
    int lane = tid & 63, w = tid >> 6;
    int q = lane >> 4, col = lane & 15;
    int r0 = blockIdx.x * MB;
    int c = r0 >> 8;
    int d0 = r0 & 255;

    if (tid < KP) {
        Crow[tid] = ((tid < HID) ? Cc[c * HID + tid] : 0.f) + bf1p[tid];
        bf2s[tid] = bf2p[tid];
    }
    {
        const float4v* wsrc = (const float4v*)wf3f;
        for (int t = tid; t < 560; t += 256) ((float4v*)wf3s)[t] = wsrc[t];
    }
    __syncthreads();   // the only barrier

    int arow = d0 + w * 16 + col;

    short8 a[KSTEPS];
#pragma unroll
    for (int s = 0; s < KSTEPS; ++s) {
        int k0 = s * 32 + q * 8;
        if (k0 < HID) {
            float4v c0 = *(const float4v*)(&Crow[k0]);
            float4v c1 = *(const float4v*)(&Crow[k0 + 4]);
            float4v dv0 = *(const float4v*)(Dc + (size_t)arow * HID + k0);
            float4v dv1 = *(const float4v*)(Dc + (size_t)arow * HID + k0 + 4);
#pragma unroll
            for (int j = 0; j < 4; ++j) {
                a[s][j]     = f2bf(fmaxf(c0[j] + dv0[j], 0.f));
                a[s][j + 4] = f2bf(fmaxf(c1[j] + dv1[j], 0.f));
            }
        } else {
#pragma unroll
            for (int j = 0; j < 8; ++j) a[s][j] = 0;
        }
    }

    float2v fw[4][5];   // [row][dose-pair]; packed fp32 (v_pk_fma_f32)
#pragma unroll
    for (int i = 0; i < 4; ++i)
#pragma unroll
        for (int u = 0; u < 5; ++u) { fw[i][u][0] = 0.f; fw[i][u][1] = 0.f; }

#pragma unroll
    for (int p = 0; p < 2; ++p) {
        float4v acc[NTP];
#pragma unroll
        for (int nt = 0; nt < NTP; ++nt) acc[nt] = 0.f;
#pragma unroll
        for (int s = 0; s < KSTEPS; ++s) {
#pragma unroll
            for (int nt = 0; nt < NTP; ++nt) {
                short8 bb = Bf[(size_t)((p * 7 + nt) * 7 + s) * 64 + lane];
                acc[nt] = __builtin_amdgcn_mfma_f32_16x16x32_bf16(a[s], bb, acc[nt], 0, 0, 0);
            }
        }
#pragma unroll
        for (int nt = 0; nt < NTP; ++nt) {
            int n = p * 112 + nt * 16 + col;
            float bb2 = bf2s[n];
            const float2v* w3p = (const float2v*)(wf3s + n * 10);
            float2v w3[5];
#pragma unroll
            for (int u = 0; u < 5; ++u) w3[u] = w3p[u];
#pragma unroll
            for (int rg = 0; rg < 4; ++rg) {
                float h2 = fmaxf(acc[nt][rg] + bb2, 0.f);
#pragma unroll
                for (int u = 0; u < 5; ++u)
                    fw[rg][u] = h2 * w3[u] + fw[rg][u];   // v_pk_fma_f32
            }
        }
    }
    // sum over the 16 lanes (n direction); keep the 9 real doses
    float red9[4][9];
#pragma unroll
    for (int i = 0; i < 4; ++i)
#pragma unroll
        for (int dd = 0; dd < 9; ++dd) {
            float v = fw[i][dd >> 1][dd & 1];
            v += __shfl_xor(v, 1, 16);
            v += __shfl_xor(v, 2, 16);
            v += __shfl_xor(v, 4, 16);
            v += __shfl_xor(v, 8, 16);
            red9[i][dd] = v;
        }
    // softplus + inclusive scan over doses (lane col = dose)
#pragma unroll
    for (int i = 0; i < 4; ++i) {
        int row = r0 + w * 16 + q * 4 + i;
        float myval = 0.f;
#pragma unroll
        for (int dd = 0; dd < 9; ++dd) myval = (col == dd) ? red9[i][dd] : myval;
        float v = (col == 0) ? myval : softplusf(myval);
        float t1 = __shfl_up(v, 1, 16); if (col >= 1) v += t1;
        float t2 = __shfl_up(v, 2, 16); if (col >= 2) v += t2;
        float t4 = __shfl_up(v, 4, 16); if (col >= 4) v += t4;
        float t8 = __shfl_up(v, 8, 16); if (col >= 8) v += t8;
        if (col < NDOSES) mu[(size_t)row * MUSTRIDE + col] = v;
    }
}

// final gather (Round-7 proven): 1 sample/thread, stride-12 mu rows, float4 loads
__global__ __launch_bounds__(256) void gather_k(const unsigned short* __restrict__ W1u,
                                                const int* __restrict__ idx,
                                                const int* __restrict__ tidx,
                                                const int* __restrict__ is_missing,
                                                const int* __restrict__ cell_map,
                                                const int* __restrict__ drug_map,
                                                const float* __restrict__ mu,
                                                void* __restrict__ out, int nB) {
    bool f32 = sniff_f32(W1u);
    int b = blockIdx.x * 256 + threadIdx.x;
    if (b >= nB) return;
    int i = idx[b];
    int cm = cell_map[i];
    int kc = (is_missing[i] != 0) ? (N_MISSING + cm) : cm;
    int kd = drug_map[tidx[b]];
    const float* mr = mu + (size_t)(kc * 256 + kd) * MUSTRIDE;
    float4v m0 = *(const float4v*)mr;
    float4v m1 = *(const float4v*)(mr + 4);
    float m8 = mr[8];
    float vals[9] = {m0[0], m0[1], m0[2], m0[3], m1[0], m1[1], m1[2], m1[3], m8};
    if (f32) {
        float* o = (float*)out + (size_t)b * NDOSES;
#pragma unroll
        for (int dd = 0; dd < 9; ++dd) o[dd] = vals[dd];
    } else {
        short* o = (short*)out + (size_t)b * NDOSES;
#pragma unroll
        for (int dd = 0; dd < 9; ++dd) o[dd] = f2bf(vals[dd]);
    }
}

// ============================ FALLBACK (Round-2, proven) ============================

__global__ void sniff_kernel(const unsigned short* __restrict__ w1bits, int* __restrict__ flag) {
    if (threadIdx.x == 0 && blockIdx.x == 0) {
        int f = 0;
        for (int i = 0; i < 512; ++i) {
            unsigned int e = (w1bits[i] >> 7) & 0xFFu;
            if (e >= 130u) f = 1;
        }
        *flag = f;
    }
}

template <bool F32>
__global__ __launch_bounds__(256) void present_kernel(const int* __restrict__ flag,
                                                      const void* __restrict__ cell_features,
                                                      const void* __restrict__ W1,
                                                      const void* __restrict__ b1,
                                                      float* __restrict__ P) {
    if (*flag != (int)F32) return;
    __shared__ float feat[NFEAT];
    int c = blockIdx.x, jb = blockIdx.y;
    for (int k = threadIdx.x; k < NFEAT; k += 256)
        feat[k] = ld<F32>(cell_features, c * NFEAT + k);
    __syncthreads();
    int j = jb * 256 + threadIdx.x;
    float acc = ld<F32>(b1, j);
    for (int k = 0; k < NFEAT; ++k)
        acc = fmaf(feat[k], ld<F32>(W1, k * CELL_EMB + j), acc);
    P[c * CELL_EMB + j] = fmaxf(acc, 0.f);
}

template <bool F32>
__global__ __launch_bounds__(256) void cc_kernel(const int* __restrict__ flag,
                                                 const float* __restrict__ P,
                                                 const void* __restrict__ missing_emb,
                                                 const void* __restrict__ Wf1,
                                                 float* __restrict__ Cc) {
    if (*flag != (int)F32) return;
    int r = blockIdx.x;
    __shared__ float x[CELL_EMB];
    __shared__ float red[4];
    if (r < N_MISSING) {
        for (int k = threadIdx.x; k < CELL_EMB; k += 256) x[k] = P[r * CELL_EMB + k];
    } else {
        for (int k = threadIdx.x; k < CELL_EMB; k += 256)
            x[k] = ld<F32>(missing_emb, (r - N_MISSING) * CELL_EMB + k);
    }
    __syncthreads();
    float ss = 0.f;
    for (int k = threadIdx.x; k < CELL_EMB; k += 256) ss += x[k] * x[k];
    for (int o = 32; o > 0; o >>= 1) ss += __shfl_down(ss, o, 64);
    if ((threadIdx.x & 63) == 0) red[threadIdx.x >> 6] = ss;
    __syncthreads();
    float inv = 1.f / fmaxf(sqrtf(red[0] + red[1] + red[2] + red[3]), 1e-12f);
    int j = threadIdx.x;
    if (j < HID) {
        float acc = 0.f;
        for (int k = 0; k < CELL_EMB; ++k)
            acc = fmaf(x[k], ld<F32>(Wf1, k * HID + j), acc);
        Cc[r * HID + j] = acc * inv;
    }
}

template <bool F32>
__global__ __launch_bounds__(256) void dc_kernel(const int* __restrict__ flag,
                                                 const void* __restrict__ drug_emb,
                                                 const void* __restrict__ Wf1,
                                                 float* __restrict__ Dc) {
    if (*flag != (int)F32) return;
    int d = blockIdx.x;
    __shared__ float x[DRUG_EMB];
    __shared__ float red[4];
    if (threadIdx.x < DRUG_EMB) x[threadIdx.x] = ld<F32>(drug_emb, d * DRUG_EMB + threadIdx.x);
    __syncthreads();
    float ss = 0.f;
    if (threadIdx.x < DRUG_EMB) ss = x[threadIdx.x] * x[threadIdx.x];
    for (int o = 32; o > 0; o >>= 1) ss += __shfl_down(ss, o, 64);
    if ((threadIdx.x & 63) == 0) red[threadIdx.x >> 6] = ss;
    __syncthreads();
    float inv = 1.f / fmaxf(sqrtf(red[0] + red[1] + red[2] + red[3]), 1e-12f);
    int j = threadIdx.x;
    if (j < HID) {
        float acc = 0.f;
        for (int k = 0; k < DRUG_EMB; ++k)
            acc = fmaf(x[k], ld<F32>(Wf1, (CELL_EMB + k) * HID + j), acc);
        Dc[d * HID + j] = acc * inv;
    }
}

template <bool F32>
__global__ __launch_bounds__(256) void main_kernel(const int* __restrict__ flag,
                                                   const int* __restrict__ idx,
                                                   const int* __restrict__ tidx,
                                                   const int* __restrict__ is_missing,
                                                   const int* __restrict__ cell_map,
                                                   const int* __restrict__ drug_map,
                                                   const float* __restrict__ Cc,
                                                   const float* __restrict__ Dc,
                                                   const void* __restrict__ bf1,
                                                   const void* __restrict__ Wf2,
                                                   const void* __restrict__ bf2,
                                                   const void* __restrict__ Wf3,
                                                   const void* __restrict__ bf3,
                                                   void* __restrict__ out, int nB) {
    if (*flag != (int)F32) return;
    __shared__ float h1t[HID][S];
    __shared__ float h2[S][HID];
    __shared__ float wf3s[HID * NDOSES];
    __shared__ float bf3s[NDOSES];
    __shared__ int keyc[S], keyd[S];
    __shared__ float fwds[S][NDOSES];

    int b0 = blockIdx.x * S;
    int tid = threadIdx.x;

    if (tid < S) {
        int b = b0 + tid;
        if (b < nB) {
            int i = idx[b];
            int cm = cell_map[i];
            keyc[tid] = (is_missing[i] != 0) ? (N_MISSING + cm) : cm;
            keyd[tid] = drug_map[tidx[b]];
        } else { keyc[tid] = 0; keyd[tid] = 0; }
    }
    for (int t = tid; t < HID * NDOSES; t += 256) wf3s[t] = ld<F32>(Wf3, t);
    if (tid < NDOSES) bf3s[tid] = ld<F32>(bf3, tid);
    __syncthreads();

    for (int t = tid; t < S * HID; t += 256) {
        int s = t / HID;
        int j = t - s * HID;
        float v = Cc[keyc[s] * HID + j] + Dc[keyd[s] * HID + j] + ld<F32>(bf1, j);
        h1t[j][s] = fmaxf(v, 0.f);
    }
    __syncthreads();

    if (tid < HID) {
        float acc[S];
#pragma unroll
        for (int s = 0; s < S; ++s) acc[s] = 0.f;
        for (int i = 0; i < HID; ++i) {
            float wv = ld<F32>(Wf2, i * HID + tid);
#pragma unroll
            for (int s = 0; s < S; ++s) acc[s] = fmaf(h1t[i][s], wv, acc[s]);
        }
        float bb = ld<F32>(bf2, tid);
#pragma unroll
        for (int s = 0; s < S; ++s) h2[s][tid] = fmaxf(acc[s] + bb, 0.f);
    }
    __syncthreads();

    if (tid < S * NDOSES) {
        int s = tid / NDOSES;
        int k = tid - s * NDOSES;
        float acc = bf3s[k];
        for (int j = 0; j < HID; ++j)
            acc = fmaf(h2[s][j], wf3s[j * NDOSES + k], acc);
        fwds[s][k] = acc;
    }
    __syncthreads();

    if (tid < S && b0 + tid < nB) {
        float m = fwds[tid][0];
        long o = (long)(b0 + tid) * NDOSES;
        if (F32) ((float*)out)[o] = m; else ((short*)out)[o] = f2bf(m);
#pragma unroll
        for (int k = 1; k < NDOSES; ++k) {
            float x = fwds[tid][k];
            m += softplusf(x);
            if (F32) ((float*)out)[o + k] = m;
            else     ((short*)out)[o + k] = f2bf(m);
        }
    }
}

// ============================ launcher ============================

extern "C" void kernel_launch(void* const* d_in, const int* in_sizes, int n_in,
                              void* d_out, int out_size, void* d_ws, size_t ws_size,
                              hipStream_t stream) {
    const int* idx        = (const int*)d_in[0];
    const int* tidx       = (const int*)d_in[1];
    const int* is_missing = (const int*)d_in[2];
    const int* cell_map   = (const int*)d_in[3];
    const int* drug_map   = (const int*)d_in[4];
    const void* CF   = d_in[5];
    const void* memb = d_in[6];
    const void* demb = d_in[7];
    const void* W1   = d_in[8];
    const void* b1   = d_in[9];
    const void* Wf1  = d_in[10];
    const void* bf1v = d_in[11];
    const void* Wf2  = d_in[12];
    const void* bf2v = d_in[13];
    const void* Wf3  = d_in[14];
    const void* bf3v = d_in[15];

    int nB = in_sizes[0];
    // layout (floats): pad 64 | Cc 40000 | Dc 51200 | Bf 25088 | bf1p 224 |
    //   bf2p 224 | wf3f 2240 | big region 819200 (P8 dead after cc_k; aliases mu)
    const size_t NEED = 938240ull * 4ull;  // ~3.75 MB

    if (ws_size >= NEED) {
        float* ws   = (float*)d_ws;
        float* Cc   = ws + 64;
        float* Dc   = ws + 40064;
        float* Bf   = ws + 91264;     // 16B aligned
        float* bf1p = ws + 116352;
        float* bf2p = ws + 116576;
        float* wf3f = ws + 116800;    // 2240 floats, 16B aligned
        float* P8   = ws + 119040;    // 819200 floats
        float* mu   = P8;             // alias: pair_k writes mu after P8 is dead

        hipLaunchKernelGGL(mega_prep_k, dim3(GP_TB_END), dim3(256), 0, stream,
                           CF, (const unsigned short*)W1, b1, demb, Wf1, Wf2,
                           bf1v, bf2v, Wf3,
                           P8, Dc, (short8*)Bf, Cc, bf1p, bf2p, wf3f);
        hipLaunchKernelGGL(cc_k, dim3(2 * N_MISSING, 8), dim3(256), 0, stream,
                           (const unsigned short*)W1, P8, memb, Wf1, Cc);
        hipLaunchKernelGGL(pair_k, dim3(800), dim3(256), 0, stream,
                           Cc, Dc, bf1p, bf2p, wf3f, (const short8*)Bf, mu);
        hipLaunchKernelGGL(gather_k, dim3((nB + 255) / 256), dim3(256), 0, stream,
                           (const unsigned short*)W1, idx, tidx, is_missing,
                           cell_map, drug_map, mu, d_out, nB);
    } else {
        // Round-2 proven fallback (ws 775 KB)
        float* ws   = (float*)d_ws;
        int*   flag = (int*)d_ws;
        float* P    = ws + 64;
        float* Cc   = P + 102400;
        float* Dc   = Cc + 40000;

        hipLaunchKernelGGL(sniff_kernel, dim3(1), dim3(64), 0, stream,
                           (const unsigned short*)W1, flag);
#define LAUNCH_BOTH(name, grid, blk, ...)                                          \
        hipLaunchKernelGGL((name<false>), grid, blk, 0, stream, flag, __VA_ARGS__);\
        hipLaunchKernelGGL((name<true>),  grid, blk, 0, stream, flag, __VA_ARGS__);
        LAUNCH_BOTH(present_kernel, dim3(N_MISSING, 4), dim3(256), CF, W1, b1, P)
        LAUNCH_BOTH(cc_kernel, dim3(2 * N_MISSING), dim3(256), P, memb, Wf1, Cc)
        LAUNCH_BOTH(dc_kernel, dim3(N_DRUGS), dim3(256), demb, Wf1, Dc)
        LAUNCH_BOTH(main_kernel, dim3((nB + S - 1) / S), dim3(256),
                    idx, tidx, is_missing, cell_map, drug_map, Cc, Dc,
                    bf1v, Wf2, bf2v, Wf3, bf3v, d_out, nB)
#undef LAUNCH_BOTH
    }
}

// Round 13
// 158.378 us; speedup vs baseline: 1.1277x; 1.1277x over previous
//
#include <hip/hip_runtime.h>
#include <hip/hip_bf16.h>

#define NFEAT 1024
#define CELL_EMB 1024
#define DRUG_EMB 128
#define HID 200
#define NDOSES 9
#define N_MISSING 100
#define N_DRUGS 256
#define S 16
#define MUSTRIDE 12

typedef __hip_bfloat16 bf16;
typedef __attribute__((ext_vector_type(8))) short short8;
typedef __attribute__((ext_vector_type(4))) short short4v;
typedef __attribute__((ext_vector_type(4))) float float4v;

__device__ __forceinline__ float bf2f(short s) {
    unsigned u = ((unsigned)(unsigned short)s) << 16;
    return __builtin_bit_cast(float, u);
}
__device__ __forceinline__ short f2bf(float f) {
    unsigned u = __builtin_bit_cast(unsigned, f);
    unsigned r = (u + 0x7FFFu + ((u >> 16) & 1u)) >> 16;
    return (short)r;
}
template <bool F32>
__device__ __forceinline__ float ld(const void* p, int i) {
    if (F32) return ((const float*)p)[i];
    return bf2f(((const short*)p)[i]);
}
__device__ __forceinline__ float ldr(const void* p, int i, bool f32) {
    return f32 ? ((const float*)p)[i] : bf2f(((const short*)p)[i]);
}
__device__ __forceinline__ float softplusf(float x) {
    return (x > 20.f) ? x : log1pf(expf(x));
}

// Inline per-wave dtype sniff: W1[0:64] as ushorts, one L2 line.
__device__ __forceinline__ bool sniff_f32(const unsigned short* __restrict__ w1) {
    int lane = threadIdx.x & 63;
    unsigned short h = w1[lane];
    bool hit = ((lane & 1) == 0) && (((h >> 7) & 0xFFu) >= 130u);
    return __ballot(hit) != 0ull;
}

// ============================ FAST PATH ============================

#define GP_PRESENT 800                 // [0,800): c=b>>3, kc=b&7
#define GP_DC_END (GP_PRESENT + 256)   // [800,1056)
#define GP_PB_END (GP_DC_END + 25)     // [1056,1081): prepb, 6272 entries
#define GP_CZ_END (GP_PB_END + 40)     // [1081,1121): Cc zero
#define GP_TB_END (GP_CZ_END + 1)      // [1121,1122): epilogue tables

// one launch: present-partials + dc + prepb + Cc-zero + tables (all independent)
__global__ __launch_bounds__(256) void mega_prep_k(const void* __restrict__ CF,
                                                   const unsigned short* __restrict__ W1u,
                                                   const void* __restrict__ b1,
                                                   const void* __restrict__ drug_emb,
                                                   const void* __restrict__ Wf1,
                                                   const void* __restrict__ Wf2,
                                                   const void* __restrict__ bf1,
                                                   const void* __restrict__ bf2,
                                                   const void* __restrict__ Wf3,
                                                   float* __restrict__ P8,
                                                   float* __restrict__ Dc,
                                                   short8* __restrict__ Bf,
                                                   float* __restrict__ Cc,
                                                   float* __restrict__ bf1p,
                                                   float* __restrict__ bf2p,
                                                   short* __restrict__ wf3b) {
    bool f32 = sniff_f32(W1u);
    const void* W1 = (const void*)W1u;
    int blk = blockIdx.x, tid = threadIdx.x;

    if (blk < GP_PRESENT) {
        __shared__ float feat[128];
        int c = blk >> 3, kc = blk & 7;
        if (tid < 128) feat[tid] = ldr(CF, c * NFEAT + kc * 128 + tid, f32);
        __syncthreads();
        int j0 = tid * 4;
        float a0 = 0.f, a1 = 0.f, a2 = 0.f, a3 = 0.f;
        if (f32) {
            const float* w = (const float*)W1 + (size_t)(kc * 128) * CELL_EMB + j0;
#pragma unroll 8
            for (int k = 0; k < 128; ++k) {
                float4v wv = *(const float4v*)(w + (size_t)k * CELL_EMB);
                float fk = feat[k];
                a0 = fmaf(fk, wv[0], a0); a1 = fmaf(fk, wv[1], a1);
                a2 = fmaf(fk, wv[2], a2); a3 = fmaf(fk, wv[3], a3);
            }
        } else {
            const short* w = (const short*)W1 + (size_t)(kc * 128) * CELL_EMB + j0;
#pragma unroll 8
            for (int k = 0; k < 128; ++k) {
                short4v wv = *(const short4v*)(w + (size_t)k * CELL_EMB);
                float fk = feat[k];
                a0 = fmaf(fk, bf2f(wv[0]), a0); a1 = fmaf(fk, bf2f(wv[1]), a1);
                a2 = fmaf(fk, bf2f(wv[2]), a2); a3 = fmaf(fk, bf2f(wv[3]), a3);
            }
        }
        if (kc == 0) {
            a0 += ldr(b1, j0 + 0, f32); a1 += ldr(b1, j0 + 1, f32);
            a2 += ldr(b1, j0 + 2, f32); a3 += ldr(b1, j0 + 3, f32);
        }
        float4v o; o[0] = a0; o[1] = a1; o[2] = a2; o[3] = a3;
        *(float4v*)(P8 + ((size_t)(kc * N_MISSING + c)) * CELL_EMB + j0) = o;
    } else if (blk < GP_DC_END) {
        __shared__ float x[DRUG_EMB];
        __shared__ float red[4];
        int d = blk - GP_PRESENT;
        if (tid < DRUG_EMB) x[tid] = ldr(drug_emb, d * DRUG_EMB + tid, f32);
        __syncthreads();
        float ss = 0.f;
        if (tid < DRUG_EMB) ss = x[tid] * x[tid];
        for (int o = 32; o > 0; o >>= 1) ss += __shfl_down(ss, o, 64);
        if ((tid & 63) == 0) red[tid >> 6] = ss;
        __syncthreads();
        float inv = 1.f / fmaxf(sqrtf(red[0] + red[1] + red[2] + red[3]), 1e-12f);
        if (tid < HID) {
            float acc = 0.f;
#pragma unroll 8
            for (int k = 0; k < DRUG_EMB; ++k)
                acc = fmaf(x[k], ldr(Wf1, (CELL_EMB + k) * HID + tid, f32), acc);
            Dc[d * HID + tid] = acc * inv;
        }
    } else if (blk < GP_PB_END) {
        int t = (blk - GP_DC_END) * 256 + tid;
        if (t < 6272) {
            int l = t & 63, chunk = t >> 6;
            int p = chunk / 49, rem = chunk - p * 49;
            int nt = rem / 7, s = rem - nt * 7;
            int n = p * 112 + nt * 16 + (l & 15);
            int k0 = s * 32 + (l >> 4) * 8;
            short8 v;
#pragma unroll
            for (int j = 0; j < 8; ++j) {
                int k = k0 + j;
                v[j] = (k < HID && n < HID) ? f2bf(ldr(Wf2, k * HID + n, f32)) : (short)0;
            }
            Bf[t] = v;
        }
    } else if (blk < GP_CZ_END) {
        int i = (blk - GP_PB_END) * 1024 + tid * 4;
        if (i < 200 * HID) {
            float4v z; z[0] = 0.f; z[1] = 0.f; z[2] = 0.f; z[3] = 0.f;
            *(float4v*)(Cc + i) = z;
        }
    } else {
        // ---- epilogue tables: bf1p/bf2p (float[224], zero-padded), wf3b (bf16[2016+pad])
        if (tid < 224) {
            bf1p[tid] = (tid < HID) ? ldr(bf1, tid, f32) : 0.f;
            bf2p[tid] = (tid < HID) ? ldr(bf2, tid, f32) : 0.f;
        }
        for (int t = tid; t < 2048; t += 256) {
            int k = t / NDOSES, dd = t - k * NDOSES;
            wf3b[t] = (t < HID * NDOSES) ? f2bf(ldr(Wf3, k * NDOSES + dd, f32)) : (short)0;
        }
    }
}

// cc_k (norm fused): block (r, kc) sums the 8 P8 partials, computes the row
// inv-norm, then Cc[r][:] += (x_chunk @ Wf1_chunk) * inv.
__global__ __launch_bounds__(256) void cc_k(const unsigned short* __restrict__ W1u,
                                            const float* __restrict__ P8,
                                            const void* __restrict__ missing_emb,
                                            const void* __restrict__ Wf1,
                                            float* __restrict__ Cc) {
    __shared__ __align__(16) float x[128];
    __shared__ float red[4];
    bool f32 = sniff_f32(W1u);
    int r = blockIdx.x, kc = blockIdx.y, tid = threadIdx.x;
    int e0 = tid * 4;
    float4v v;
    if (r < N_MISSING) {
        v[0] = 0.f; v[1] = 0.f; v[2] = 0.f; v[3] = 0.f;
#pragma unroll
        for (int p = 0; p < 8; ++p) {
            float4v t = *(const float4v*)(P8 + ((size_t)(p * N_MISSING + r)) * CELL_EMB + e0);
            v[0] += t[0]; v[1] += t[1]; v[2] += t[2]; v[3] += t[3];
        }
        v[0] = fmaxf(v[0], 0.f); v[1] = fmaxf(v[1], 0.f);
        v[2] = fmaxf(v[2], 0.f); v[3] = fmaxf(v[3], 0.f);
    } else if (f32) {
        v = *(const float4v*)((const float*)missing_emb + (size_t)(r - N_MISSING) * CELL_EMB + e0);
    } else {
        short4v s = *(const short4v*)((const short*)missing_emb + (size_t)(r - N_MISSING) * CELL_EMB + e0);
        v[0] = bf2f(s[0]); v[1] = bf2f(s[1]); v[2] = bf2f(s[2]); v[3] = bf2f(s[3]);
    }
    if ((tid >> 5) == kc) *(float4v*)(x + (e0 - kc * 128)) = v;
    float ss = v[0] * v[0] + v[1] * v[1] + v[2] * v[2] + v[3] * v[3];
    for (int o = 32; o > 0; o >>= 1) ss += __shfl_down(ss, o, 64);
    if ((tid & 63) == 0) red[tid >> 6] = ss;
    __syncthreads();
    float inv = 1.f / fmaxf(sqrtf(red[0] + red[1] + red[2] + red[3]), 1e-12f);
    if (tid < HID) {
        float acc = 0.f;
        if (f32) {
            const float* w = (const float*)Wf1 + (size_t)(kc * 128) * HID + tid;
#pragma unroll 8
            for (int k = 0; k < 128; ++k)
                acc = fmaf(x[k], w[(size_t)k * HID], acc);
        } else {
            const short* w = (const short*)Wf1 + (size_t)(kc * 128) * HID + tid;
#pragma unroll 8
            for (int k = 0; k < 128; ++k)
                acc = fmaf(x[k], bf2f(w[(size_t)k * HID]), acc);
        }
        atomicAdd(&Cc[r * HID + tid], acc * inv);
    }
}

// ---- pair MFMA kernel (R11-proven): MB=64, A-frags in registers reused across
// both passes; global Bf reads; prologue is pure vector copies from tables.
#define KSTEPS 7
#define NTP 7
#define KP 224
#define MB 64

__global__ __launch_bounds__(256) void pair_k(const float* __restrict__ Cc,
                                              const float* __restrict__ Dc,
                                              const float* __restrict__ bf1p,
                                              const float* __restrict__ bf2p,
                                              const short8* __restrict__ wf3b8,
                                              const short8* __restrict__ Bf,
                                              float* __restrict__ mu) {
    __shared__ float Crow[KP];
    __shared__ float bf2s[KP];
    __shared__ __align__(16) short wf3s[2016];
    int tid = threadIdx.x;
    int lane = tid & 63, w = tid >> 6;
    int q = lane >> 4, col = lane & 15;
    int r0 = blockIdx.x * MB;
    int c = r0 >> 8;
    int d0 = r0 & 255;

    if (tid < KP) {
        Crow[tid] = ((tid < HID) ? Cc[c * HID + tid] : 0.f) + bf1p[tid];
        bf2s[tid] = bf2p[tid];
    }
    if (tid < 252) ((short8*)wf3s)[tid] = wf3b8[tid];
    __syncthreads();   // the only barrier

    int arow = d0 + w * 16 + col;

    short8 a[KSTEPS];
#pragma unroll
    for (int s = 0; s < KSTEPS; ++s) {
        int k0 = s * 32 + q * 8;
        if (k0 < HID) {
            float4v c0 = *(const float4v*)(&Crow[k0]);
            float4v c1 = *(const float4v*)(&Crow[k0 + 4]);
            float4v dv0 = *(const float4v*)(Dc + (size_t)arow * HID + k0);
            float4v dv1 = *(const float4v*)(Dc + (size_t)arow * HID + k0 + 4);
#pragma unroll
            for (int j = 0; j < 4; ++j) {
                a[s][j]     = f2bf(fmaxf(c0[j] + dv0[j], 0.f));
                a[s][j + 4] = f2bf(fmaxf(c1[j] + dv1[j], 0.f));
            }
        } else {
#pragma unroll
            for (int j = 0; j < 8; ++j) a[s][j] = 0;
        }
    }

    float fw[4][9];
#pragma unroll
    for (int i = 0; i < 4; ++i)
#pragma unroll
        for (int dd = 0; dd < 9; ++dd) fw[i][dd] = 0.f;

    for (int p = 0; p < 2; ++p) {
        float4v acc[NTP];
#pragma unroll
        for (int nt = 0; nt < NTP; ++nt) acc[nt] = 0.f;
#pragma unroll
        for (int s = 0; s < KSTEPS; ++s) {
#pragma unroll
            for (int nt = 0; nt < NTP; ++nt) {
                short8 bb = Bf[(size_t)((p * 7 + nt) * 7 + s) * 64 + lane];
                acc[nt] = __builtin_amdgcn_mfma_f32_16x16x32_bf16(a[s], bb, acc[nt], 0, 0, 0);
            }
        }
#pragma unroll
        for (int nt = 0; nt < NTP; ++nt) {
            int n = p * 112 + nt * 16 + col;
            float bb2 = bf2s[n];
            float w3[9];
#pragma unroll
            for (int dd = 0; dd < 9; ++dd) w3[dd] = bf2f(wf3s[n * NDOSES + dd]);
#pragma unroll
            for (int rg = 0; rg < 4; ++rg) {
                float h2 = fmaxf(acc[nt][rg] + bb2, 0.f);
#pragma unroll
                for (int dd = 0; dd < 9; ++dd)
                    fw[rg][dd] = fmaf(h2, w3[dd], fw[rg][dd]);
            }
        }
    }
#pragma unroll
    for (int i = 0; i < 4; ++i)
#pragma unroll
        for (int dd = 0; dd < 9; ++dd) {
            float v = fw[i][dd];
            v += __shfl_xor(v, 1, 16);
            v += __shfl_xor(v, 2, 16);
            v += __shfl_xor(v, 4, 16);
            v += __shfl_xor(v, 8, 16);
            fw[i][dd] = v;
        }
#pragma unroll
    for (int i = 0; i < 4; ++i) {
        int row = r0 + w * 16 + q * 4 + i;
        float myval = 0.f;
#pragma unroll
        for (int dd = 0; dd < 9; ++dd) myval = (col == dd) ? fw[i][dd] : myval;
        float v = (col == 0) ? myval : softplusf(myval);
        float t1 = __shfl_up(v, 1, 16); if (col >= 1) v += t1;
        float t2 = __shfl_up(v, 2, 16); if (col >= 2) v += t2;
        float t4 = __shfl_up(v, 4, 16); if (col >= 4) v += t4;
        float t8 = __shfl_up(v, 8, 16); if (col >= 8) v += t8;
        if (col < NDOSES) mu[(size_t)row * MUSTRIDE + col] = v;
    }
}

// final gather (Round-7 proven): 1 sample/thread, stride-12 mu rows, float4 loads
__global__ __launch_bounds__(256) void gather_k(const unsigned short* __restrict__ W1u,
                                                const int* __restrict__ idx,
                                                const int* __restrict__ tidx,
                                                const int* __restrict__ is_missing,
                                                const int* __restrict__ cell_map,
                                                const int* __restrict__ drug_map,
                                                const float* __restrict__ mu,
                                                void* __restrict__ out, int nB) {
    bool f32 = sniff_f32(W1u);
    int b = blockIdx.x * 256 + threadIdx.x;
    if (b >= nB) return;
    int i = idx[b];
    int cm = cell_map[i];
    int kc = (is_missing[i] != 0) ? (N_MISSING + cm) : cm;
    int kd = drug_map[tidx[b]];
    const float* mr = mu + (size_t)(kc * 256 + kd) * MUSTRIDE;
    float4v m0 = *(const float4v*)mr;
    float4v m1 = *(const float4v*)(mr + 4);
    float m8 = mr[8];
    float vals[9] = {m0[0], m0[1], m0[2], m0[3], m1[0], m1[1], m1[2], m1[3], m8};
    if (f32) {
        float* o = (float*)out + (size_t)b * NDOSES;
#pragma unroll
        for (int dd = 0; dd < 9; ++dd) o[dd] = vals[dd];
    } else {
        short* o = (short*)out + (size_t)b * NDOSES;
#pragma unroll
        for (int dd = 0; dd < 9; ++dd) o[dd] = f2bf(vals[dd]);
    }
}

// ============================ FALLBACK (Round-2, proven) ============================

__global__ void sniff_kernel(const unsigned short* __restrict__ w1bits, int* __restrict__ flag) {
    if (threadIdx.x == 0 && blockIdx.x == 0) {
        int f = 0;
        for (int i = 0; i < 512; ++i) {
            unsigned int e = (w1bits[i] >> 7) & 0xFFu;
            if (e >= 130u) f = 1;
        }
        *flag = f;
    }
}

template <bool F32>
__global__ __launch_bounds__(256) void present_kernel(const int* __restrict__ flag,
                                                      const void* __restrict__ cell_features,
                                                      const void* __restrict__ W1,
                                                      const void* __restrict__ b1,
                                                      float* __restrict__ P) {
    if (*flag != (int)F32) return;
    __shared__ float feat[NFEAT];
    int c = blockIdx.x, jb = blockIdx.y;
    for (int k = threadIdx.x; k < NFEAT; k += 256)
        feat[k] = ld<F32>(cell_features, c * NFEAT + k);
    __syncthreads();
    int j = jb * 256 + threadIdx.x;
    float acc = ld<F32>(b1, j);
    for (int k = 0; k < NFEAT; ++k)
        acc = fmaf(feat[k], ld<F32>(W1, k * CELL_EMB + j), acc);
    P[c * CELL_EMB + j] = fmaxf(acc, 0.f);
}

template <bool F32>
__global__ __launch_bounds__(256) void cc_kernel(const int* __restrict__ flag,
                                                 const float* __restrict__ P,
                                                 const void* __restrict__ missing_emb,
                                                 const void* __restrict__ Wf1,
                                                 float* __restrict__ Cc) {
    if (*flag != (int)F32) return;
    int r = blockIdx.x;
    __shared__ float x[CELL_EMB];
    __shared__ float red[4];
    if (r < N_MISSING) {
        for (int k = threadIdx.x; k < CELL_EMB; k += 256) x[k] = P[r * CELL_EMB + k];
    } else {
        for (int k = threadIdx.x; k < CELL_EMB; k += 256)
            x[k] = ld<F32>(missing_emb, (r - N_MISSING) * CELL_EMB + k);
    }
    __syncthreads();
    float ss = 0.f;
    for (int k = threadIdx.x; k < CELL_EMB; k += 256) ss += x[k] * x[k];
    for (int o = 32; o > 0; o >>= 1) ss += __shfl_down(ss, o, 64);
    if ((threadIdx.x & 63) == 0) red[threadIdx.x >> 6] = ss;
    __syncthreads();
    float inv = 1.f / fmaxf(sqrtf(red[0] + red[1] + red[2] + red[3]), 1e-12f);
    int j = threadIdx.x;
    if (j < HID) {
        float acc = 0.f;
        for (int k = 0; k < CELL_EMB; ++k)
            acc = fmaf(x[k], ld<F32>(Wf1, k * HID + j), acc);
        Cc[r * HID + j] = acc * inv;
    }
}

template <bool F32>
__global__ __launch_bounds__(256) void dc_kernel(const int* __restrict__ flag,
                                                 const void* __restrict__ drug_emb,
                                                 const void* __restrict__ Wf1,
                                                 float* __restrict__ Dc) {
    if (*flag != (int)F32) return;
    int d = blockIdx.x;
    __shared__ float x[DRUG_EMB];
    __shared__ float red[4];
    if (threadIdx.x < DRUG_EMB) x[threadIdx.x] = ld<F32>(drug_emb, d * DRUG_EMB + threadIdx.x);
    __syncthreads();
    float ss = 0.f;
    if (threadIdx.x < DRUG_EMB) ss = x[threadIdx.x] * x[threadIdx.x];
    for (int o = 32; o > 0; o >>= 1) ss += __shfl_down(ss, o, 64);
    if ((threadIdx.x & 63) == 0) red[threadIdx.x >> 6] = ss;
    __syncthreads();
    float inv = 1.f / fmaxf(sqrtf(red[0] + red[1] + red[2] + red[3]), 1e-12f);
    int j = threadIdx.x;
    if (j < HID) {
        float acc = 0.f;
        for (int k = 0; k < DRUG_EMB; ++k)
            acc = fmaf(x[k], ld<F32>(Wf1, (CELL_EMB + k) * HID + j), acc);
        Dc[d * HID + j] = acc * inv;
    }
}

template <bool F32>
__global__ __launch_bounds__(256) void main_kernel(const int* __restrict__ flag,
                                                   const int* __restrict__ idx,
                                                   const int* __restrict__ tidx,
                                                   const int* __restrict__ is_missing,
                                                   const int* __restrict__ cell_map,
                                                   const int* __restrict__ drug_map,
                                                   const float* __restrict__ Cc,
                                                   const float* __restrict__ Dc,
                                                   const void* __restrict__ bf1,
                                                   const void* __restrict__ Wf2,
                                                   const void* __restrict__ bf2,
                                                   const void* __restrict__ Wf3,
                                                   const void* __restrict__ bf3,
                                                   void* __restrict__ out, int nB) {
    if (*flag != (int)F32) return;
    __shared__ float h1t[HID][S];
    __shared__ float h2[S][HID];
    __shared__ float wf3s[HID * NDOSES];
    __shared__ float bf3s[NDOSES];
    __shared__ int keyc[S], keyd[S];
    __shared__ float fwds[S][NDOSES];

    int b0 = blockIdx.x * S;
    int tid = threadIdx.x;

    if (tid < S) {
        int b = b0 + tid;
        if (b < nB) {
            int i = idx[b];
            int cm = cell_map[i];
            keyc[tid] = (is_missing[i] != 0) ? (N_MISSING + cm) : cm;
            keyd[tid] = drug_map[tidx[b]];
        } else { keyc[tid] = 0; keyd[tid] = 0; }
    }
    for (int t = tid; t < HID * NDOSES; t += 256) wf3s[t] = ld<F32>(Wf3, t);
    if (tid < NDOSES) bf3s[tid] = ld<F32>(bf3, tid);
    __syncthreads();

    for (int t = tid; t < S * HID; t += 256) {
        int s = t / HID;
        int j = t - s * HID;
        float v = Cc[keyc[s] * HID + j] + Dc[keyd[s] * HID + j] + ld<F32>(bf1, j);
        h1t[j][s] = fmaxf(v, 0.f);
    }
    __syncthreads();

    if (tid < HID) {
        float acc[S];
#pragma unroll
        for (int s = 0; s < S; ++s) acc[s] = 0.f;
        for (int i = 0; i < HID; ++i) {
            float wv = ld<F32>(Wf2, i * HID + tid);
#pragma unroll
            for (int s = 0; s < S; ++s) acc[s] = fmaf(h1t[i][s], wv, acc[s]);
        }
        float bb = ld<F32>(bf2, tid);
#pragma unroll
        for (int s = 0; s < S; ++s) h2[s][tid] = fmaxf(acc[s] + bb, 0.f);
    }
    __syncthreads();

    if (tid < S * NDOSES) {
        int s = tid / NDOSES;
        int k = tid - s * NDOSES;
        float acc = bf3s[k];
        for (int j = 0; j < HID; ++j)
            acc = fmaf(h2[s][j], wf3s[j * NDOSES + k], acc);
        fwds[s][k] = acc;
    }
    __syncthreads();

    if (tid < S && b0 + tid < nB) {
        float m = fwds[tid][0];
        long o = (long)(b0 + tid) * NDOSES;
        if (F32) ((float*)out)[o] = m; else ((short*)out)[o] = f2bf(m);
#pragma unroll
        for (int k = 1; k < NDOSES; ++k) {
            float x = fwds[tid][k];
            m += softplusf(x);
            if (F32) ((float*)out)[o + k] = m;
            else     ((short*)out)[o + k] = f2bf(m);
        }
    }
}

// ============================ launcher ============================

extern "C" void kernel_launch(void* const* d_in, const int* in_sizes, int n_in,
                              void* d_out, int out_size, void* d_ws, size_t ws_size,
                              hipStream_t stream) {
    const int* idx        = (const int*)d_in[0];
    const int* tidx       = (const int*)d_in[1];
    const int* is_missing = (const int*)d_in[2];
    const int* cell_map   = (const int*)d_in[3];
    const int* drug_map   = (const int*)d_in[4];
    const void* CF   = d_in[5];
    const void* memb = d_in[6];
    const void* demb = d_in[7];
    const void* W1   = d_in[8];
    const void* b1   = d_in[9];
    const void* Wf1  = d_in[10];
    const void* bf1v = d_in[11];
    const void* Wf2  = d_in[12];
    const void* bf2v = d_in[13];
    const void* Wf3  = d_in[14];
    const void* bf3v = d_in[15];

    int nB = in_sizes[0];
    // layout (floats): pad 64 | Cc 40000 | Dc 51200 | Bf 25088 | bf1p 224 |
    //   bf2p 224 | wf3b 1024 | big region 819200 (P8 dead after cc_k; aliases mu)
    const size_t NEED = 937088ull * 4ull;  // ~3.75 MB

    if (ws_size >= NEED) {
        float* ws   = (float*)d_ws;
        float* Cc   = ws + 64;
        float* Dc   = ws + 40064;
        float* Bf   = ws + 91264;     // 16B aligned
        float* bf1p = ws + 116352;
        float* bf2p = ws + 116576;
        float* wf3b = ws + 116800;    // 1024 floats = 2048 shorts, 16B aligned
        float* P8   = ws + 117888;    // 819200 floats
        float* mu   = P8;             // alias: pair_k writes mu after P8 is dead

        hipLaunchKernelGGL(mega_prep_k, dim3(GP_TB_END), dim3(256), 0, stream,
                           CF, (const unsigned short*)W1, b1, demb, Wf1, Wf2,
                           bf1v, bf2v, Wf3,
                           P8, Dc, (short8*)Bf, Cc, bf1p, bf2p, (short*)wf3b);
        hipLaunchKernelGGL(cc_k, dim3(2 * N_MISSING, 8), dim3(256), 0, stream,
                           (const unsigned short*)W1, P8, memb, Wf1, Cc);
        hipLaunchKernelGGL(pair_k, dim3(800), dim3(256), 0, stream,
                           Cc, Dc, bf1p, bf2p, (const short8*)wf3b,
                           (const short8*)Bf, mu);
        hipLaunchKernelGGL(gather_k, dim3((nB + 255) / 256), dim3(256), 0, stream,
                           (const unsigned short*)W1, idx, tidx, is_missing,
                           cell_map, drug_map, mu, d_out, nB);
    } else {
        // Round-2 proven fallback (ws 775 KB)
        float* ws   = (float*)d_ws;
        int*   flag = (int*)d_ws;
        float* P    = ws + 64;
        float* Cc   = P + 102400;
        float* Dc   = Cc + 40000;

        hipLaunchKernelGGL(sniff_kernel, dim3(1), dim3(64), 0, stream,
                           (const unsigned short*)W1, flag);
#define LAUNCH_BOTH(name, grid, blk, ...)                                          \
        hipLaunchKernelGGL((name<false>), grid, blk, 0, stream, flag, __VA_ARGS__);\
        hipLaunchKernelGGL((name<true>),  grid, blk, 0, stream, flag, __VA_ARGS__);
        LAUNCH_BOTH(present_kernel, dim3(N_MISSING, 4), dim3(256), CF, W1, b1, P)
        LAUNCH_BOTH(cc_kernel, dim3(2 * N_MISSING), dim3(256), P, memb, Wf1, Cc)
        LAUNCH_BOTH(dc_kernel, dim3(N_DRUGS), dim3(256), demb, Wf1, Dc)
        LAUNCH_BOTH(main_kernel, dim3((nB + S - 1) / S), dim3(256),
                    idx, tidx, is_missing, cell_map, drug_map, Cc, Dc,
                    bf1v, Wf2, bf2v, Wf3, bf3v, d_out, nB)
#undef LAUNCH_BOTH
    }
}